// Round 2
// baseline (194.148 us; speedup 1.0000x reference)
//
#include <hip/hip_runtime.h>
#include <hip/hip_bf16.h>

typedef __attribute__((ext_vector_type(8))) short s8v;    // 8 bf16
typedef __attribute__((ext_vector_type(4))) short s4v;    // 4 bf16
typedef __attribute__((ext_vector_type(4))) float f4v;    // 4 fp32

__device__ __forceinline__ void g2lds16(const void* g, void* l) {
  __builtin_amdgcn_global_load_lds(
      (__attribute__((address_space(1))) void*)(g),
      (__attribute__((address_space(3))) void*)(l), 16, 0, 0);
}

__device__ __forceinline__ short f2bf(float f) {
  __hip_bfloat16 h = __float2bfloat16(f);
  return *reinterpret_cast<short*>(&h);
}

#define FENCE asm volatile("" ::: "memory")
#define BARRIER do { FENCE; __builtin_amdgcn_s_barrier(); FENCE; } while (0)
#define WAITVM(N) asm volatile("s_waitcnt vmcnt(" #N ")" ::: "memory")

// ---------------- K0: fused x->bf16 cvt  +  W transpose->bf16 ----------------
__global__ void k_prep(const float* __restrict__ x, const float* __restrict__ W,
                       __hip_bfloat16* __restrict__ xb, __hip_bfloat16* __restrict__ Wt) {
  int bx = blockIdx.x;
  if (bx < 4096) {
    int i = (bx * 256 + threadIdx.x) * 4;
    float4 v = *(const float4*)(x + i);
    __hip_bfloat16 o[4] = {__float2bfloat16(v.x), __float2bfloat16(v.y),
                           __float2bfloat16(v.z), __float2bfloat16(v.w)};
    *(uint2*)(xb + i) = *(const uint2*)(o);
  } else {
    __shared__ float tile[32][33];
    int r = bx - 4096;            // 0..3071 = 32 x 96
    int rt = r / 96;              // over 1024/32
    int ct = r - rt * 96;         // over 3072/32
    int c0 = ct * 32, r0 = rt * 32;
    int tr = threadIdx.x >> 5, tc = threadIdx.x & 31;
#pragma unroll
    for (int i = 0; i < 32; i += 8)
      tile[tr + i][tc] = W[(size_t)(r0 + tr + i) * 3072 + c0 + tc];
    __syncthreads();
#pragma unroll
    for (int i = 0; i < 32; i += 8)
      Wt[(size_t)(c0 + tr + i) * 1024 + r0 + tc] = __float2bfloat16(tile[tc][tr + i]);
  }
}

// ---------------- K1: GEMM + fused QKV scatter epilogue ----------------
// m201-template port: 256x256 tile, BK=64, 8 waves, 512 thr, 128KB LDS
// double buffer (2 bufs x {A-half0,A-half1,B-half0,B-half1} x 16KB).
// 8 phases per 2 K-tiles; 16 MFMA/phase; 2 raw s_barrier/phase;
// counted vmcnt(2) at phases 4 and 8 ONLY (never 0 in the loop).
//
// Wave decomposition: wv2 = wave>>2 picks a 64-row sub-strip INSIDE each
// A-half (so m-frags 0-3 read only A-half0, 4-7 only A-half1 for every
// wave -> A-halves die at phase boundaries). wn = (wave&3)*64 picks the
// col group (waves own one B-half for all 4 phases -> B dies at tile end).
//
// Per-iter stage schedule (half-tile = 2 g2lds16/thread):
//   p1: buf1.{A1,B0,B1} <- tile 2i+1   (6 loads)  [dead from p1]
//   p3: buf0.A0         <- tile 2i+2   (2)        [A0 dead from p3]
//   p5: buf0.{A1,B0,B1} <- tile 2i+2   (6)        [dead from p5]
//   p7: buf1.A0         <- tile 2i+3   (2)        [dead from p7]
// Gates: p4 vmcnt(2) drains prev-p7 + p1 (first reads p5); p8 vmcnt(2)
// drains p3 + p5 (first reads p1 of next iter). Min flight = 3 phases.
__global__ __launch_bounds__(512, 2) void k_gemm(const __hip_bfloat16* __restrict__ A,
                                                 const __hip_bfloat16* __restrict__ Bt,
                                                 const float* __restrict__ bias,
                                                 __hip_bfloat16* __restrict__ Q,
                                                 __hip_bfloat16* __restrict__ K,
                                                 __hip_bfloat16* __restrict__ Vt) {
  __shared__ __align__(16) __hip_bfloat16 As[2][2][128 * 64];  // [buf][half][row*64]
  __shared__ __align__(16) __hip_bfloat16 Bs[2][2][128 * 64];
  const int tid = threadIdx.x;
  const int lane = tid & 63, wave = tid >> 6;      // 8 waves
  const int m0 = blockIdx.y * 256, n0 = blockIdx.x * 256;
  const int wv2 = wave >> 2;                       // m sub-strip in each half
  const int wn = (wave & 3) * 64;                  // wave col group
  const int bhi = wn >> 7;                         // B half owned by wave
  const int bRow = wn & 127;                       // row base inside B half
  const int lrow = lane & 15, quad = lane >> 4;
  const int lx7 = lrow & 7;

  f4v acc[8][4] = {};

  auto stA = [&](int buf, int h, int kt) {
#pragma unroll
    for (int c = 0; c < 2; ++c) {
      int e = c * 4096 + tid * 8;                  // elem idx in 128x64 half
      int p = e >> 6;                              // row
      int sl = (e >> 3) & 7;                       // 8-elem slot
      g2lds16(A + (size_t)(m0 + h * 128 + p) * 1024 + kt * 64 + ((sl ^ (p & 7)) << 3),
              &As[buf][h][e]);
    }
  };
  auto stB = [&](int buf, int h, int kt) {
#pragma unroll
    for (int c = 0; c < 2; ++c) {
      int e = c * 4096 + tid * 8;
      int p = e >> 6;
      int sl = (e >> 3) & 7;
      g2lds16(Bt + (size_t)(n0 + h * 128 + p) * 1024 + kt * 64 + ((sl ^ (p & 7)) << 3),
              &Bs[buf][h][e]);
    }
  };

#define PHASE(BUF, MH, NH, STAGE, GATE) do {                                        \
    s8v af_[4][2], bf_[2][2];                                                       \
    _Pragma("unroll") for (int mq = 0; mq < 4; ++mq)                                \
      _Pragma("unroll") for (int ks = 0; ks < 2; ++ks)                              \
        af_[mq][ks] = *(const s8v*)(&As[BUF][MH][(wv2 * 64 + mq * 16 + lrow) * 64 + \
                                                 (((ks * 4 + quad) ^ lx7) << 3)]);  \
    _Pragma("unroll") for (int nq = 0; nq < 2; ++nq)                                \
      _Pragma("unroll") for (int ks = 0; ks < 2; ++ks)                              \
        bf_[nq][ks] = *(const s8v*)(&Bs[BUF][bhi][(bRow + (NH * 2 + nq) * 16 + lrow) * 64 + \
                                                  (((ks * 4 + quad) ^ lx7) << 3)]); \
    STAGE                                                                           \
    BARRIER;                                                                        \
    asm volatile("s_waitcnt lgkmcnt(0)" ::: "memory");                              \
    __builtin_amdgcn_sched_barrier(0);                                              \
    __builtin_amdgcn_s_setprio(1);                                                  \
    _Pragma("unroll") for (int ks = 0; ks < 2; ++ks)                                \
      _Pragma("unroll") for (int mq = 0; mq < 4; ++mq)                              \
        _Pragma("unroll") for (int nq = 0; nq < 2; ++nq)                            \
          acc[MH * 4 + mq][NH * 2 + nq] = __builtin_amdgcn_mfma_f32_16x16x32_bf16(  \
              af_[mq][ks], bf_[nq][ks], acc[MH * 4 + mq][NH * 2 + nq], 0, 0, 0);    \
    __builtin_amdgcn_s_setprio(0);                                                  \
    GATE                                                                            \
    BARRIER;                                                                        \
  } while (0)

  // prologue: buf0 <- tile 0 (8 loads), buf1.A0 <- tile 1 (2 loads, stays in flight)
  stA(0, 0, 0); stA(0, 1, 0); stB(0, 0, 0); stB(0, 1, 0);
  stA(1, 0, 1);
  WAITVM(2);
  BARRIER;

  for (int i = 0; i < 8; ++i) {
    const int t1 = 2 * i + 1;                          // <= 15 always
    const int t2 = (2 * i + 2 < 16) ? 2 * i + 2 : 15;  // clamp keeps vmcnt algebra
    const int t3 = (2 * i + 3 < 16) ? 2 * i + 3 : 15;
    PHASE(0, 0, 0, { stA(1, 1, t1); stB(1, 0, t1); stB(1, 1, t1); }, );  // p1
    PHASE(0, 0, 1, , );                                                   // p2
    PHASE(0, 1, 0, { stA(0, 0, t2); }, );                                 // p3
    PHASE(0, 1, 1, , WAITVM(2); );                                        // p4
    PHASE(1, 0, 0, { stA(0, 1, t2); stB(0, 0, t2); stB(0, 1, t2); }, );   // p5
    PHASE(1, 0, 1, , );                                                   // p6
    PHASE(1, 1, 0, { stA(1, 0, t3); }, );                                 // p7
    PHASE(1, 1, 1, , WAITVM(2); );                                        // p8
  }
#undef PHASE

  // epilogue: per-row destination decode, d-packed 8B stores for Q/K
  const int cw = n0 + wn;            // multiple of 64 -> c10 wave-uniform
  const int c10 = cw >> 10;          // 0..2
  const int d0 = (cw & 1023) >> 4;   // multiple of 4
  const int h = lrow;
  float bv[4];
#pragma unroll
  for (int ni = 0; ni < 4; ++ni) bv[ni] = bias[cw + ni * 16 + lrow];

#pragma unroll
  for (int mi = 0; mi < 8; ++mi) {
    int rbase = m0 + (mi >> 2) * 128 + wv2 * 64 + (mi & 3) * 16 + quad * 4;
#pragma unroll
    for (int reg = 0; reg < 4; ++reg) {
      int rr = rbase + reg;
      int u = 3 * rr + c10;
      int s = u >> 12;
      int b = (u >> 11) & 1;
      int tt = u & 2047;
      if (s < 2) {
        __hip_bfloat16* dst = (s == 0) ? Q : K;
        s4v pk;
#pragma unroll
        for (int ni = 0; ni < 4; ++ni) pk[ni] = f2bf(acc[mi][ni][reg] + bv[ni]);
        *(s4v*)(dst + ((size_t)(b * 16 + h) * 2048 + tt) * 64 + d0) = pk;
      } else {
#pragma unroll
        for (int ni = 0; ni < 4; ++ni)
          Vt[((size_t)(b * 16 + h) * 64 + d0 + ni) * 2048 + tt] =
              __float2bfloat16(acc[mi][ni][reg] + bv[ni]);
      }
    }
  }
}

// ---------------- K2: causal flash attention ----------------
// (unchanged)
__global__ __launch_bounds__(256, 3) void k_attn(const __hip_bfloat16* __restrict__ Q,
                                                 const __hip_bfloat16* __restrict__ K,
                                                 const __hip_bfloat16* __restrict__ Vt,
                                                 float* __restrict__ out) {
  __shared__ __align__(16) char lds[2][16384];  // per buf: K tile 8KB | V tile 8KB

  const int tid = threadIdx.x;
  const int lane = tid & 63, w = tid >> 6;
  const int l = lane & 15, q = lane >> 4, lx = l & 7;

  const int bid = blockIdx.x;           // 1024 blocks
  const int xcd = bid & 7;
  const int idx = bid >> 3;             // 0..127
  const int bh = xcd + 8 * (idx & 3);   // 4 bh per XCD -> 2MB K+V in its L2
  const int qb = 31 - (idx >> 2);       // heavy blocks first; tiles 0..qb

  const char* Kb = (const char*)(K + (size_t)bh * 131072);
  const char* Vb = (const char*)(Vt + (size_t)bh * 131072);
  const __hip_bfloat16* Qp = Q + (size_t)bh * 131072 + (size_t)qb * 4096;

  // Q fragment (load once): B[n=t][k], t = qb*64 + w*16 + l
  s8v Qf[2];
#pragma unroll
  for (int kh = 0; kh < 2; ++kh)
    Qf[kh] = *(const s8v*)(Qp + (size_t)(w * 16 + l) * 64 + kh * 32 + q * 8);

  f4v O[4] = {};
  float m = -INFINITY, lsum = 0.f;
  const float c1 = 0.125f * 1.44269504088896f;  // scale * log2(e)
  const int tg = qb * 64 + w * 16 + l;          // this lane's global Q row

  auto stage = [&](int j, char* buf) {
#pragma unroll
    for (int c = 0; c < 4; ++c) {
      int chunk = w * 4 + c;            // 0..15
      int ls = chunk * 64 + lane;       // 16B-slot index
      if (chunk < 8) {                  // K tile: LDS[row][kb] = K[row][kb ^ (row&7)]
        int row = ls >> 3, kb = ls & 7;
        g2lds16(Kb + (size_t)j * 8192 + row * 128 + ((kb ^ (row & 7)) << 4),
                buf + ls * 16);
      } else {                          // V tile: LDS[d][kb] = V^T[d][kb ^ (d&7)]
        int ls2 = ls - 512;
        int d = ls2 >> 3, kb = ls2 & 7;
        g2lds16(Vb + (size_t)d * 4096 + (size_t)j * 128 + ((kb ^ (d & 7)) << 4),
                buf + 8192 + ls2 * 16);
      }
    }
  };

  stage(0, lds[0]);
  __syncthreads();

  for (int j = 0; j <= qb; ++j) {
    const char* Kl = lds[j & 1];
    const char* Vl = Kl + 8192;
    if (j < qb) stage(j + 1, lds[(j + 1) & 1]);

    // S^T: A = K rows (m = s_local), B = Q (n = t)
    f4v S[4];
#pragma unroll
    for (int nt = 0; nt < 4; ++nt) {
      const char* rowp = Kl + (nt * 16 + l) * 128;
      s8v k0 = *(const s8v*)(rowp + ((q ^ lx) << 4));
      s8v k1 = *(const s8v*)(rowp + (((4 + q) ^ lx) << 4));
      f4v z = {0.f, 0.f, 0.f, 0.f};
      z = __builtin_amdgcn_mfma_f32_16x16x32_bf16(k0, Qf[0], z, 0, 0, 0);
      z = __builtin_amdgcn_mfma_f32_16x16x32_bf16(k1, Qf[1], z, 0, 0, 0);
      S[nt] = z;
    }

    float p2[4][4];
#pragma unroll
    for (int nt = 0; nt < 4; ++nt)
#pragma unroll
      for (int r = 0; r < 4; ++r) p2[nt][r] = S[nt][r] * c1;
    if (j == qb) {
#pragma unroll
      for (int nt = 0; nt < 4; ++nt)
#pragma unroll
        for (int r = 0; r < 4; ++r)
          if (j * 64 + nt * 16 + q * 4 + r > tg) p2[nt][r] = -1e30f;
    }

    float mx = p2[0][0];
#pragma unroll
    for (int nt = 0; nt < 4; ++nt)
#pragma unroll
      for (int r = 0; r < 4; ++r) mx = fmaxf(mx, p2[nt][r]);
    mx = fmaxf(mx, __shfl_xor(mx, 16));
    mx = fmaxf(mx, __shfl_xor(mx, 32));
    float mn = fmaxf(m, mx);
    float alpha = exp2f(m - mn);
    m = mn;

    float rs = 0.f;
    s4v Pf[4];
#pragma unroll
    for (int nt = 0; nt < 4; ++nt)
#pragma unroll
      for (int r = 0; r < 4; ++r) {
        float e = exp2f(p2[nt][r] - mn);
        rs += e;
        Pf[nt][r] = f2bf(e);
      }
    rs += __shfl_xor(rs, 16);
    rs += __shfl_xor(rs, 32);
    lsum = lsum * alpha + rs;
#pragma unroll
    for (int dt = 0; dt < 4; ++dt) O[dt] *= alpha;

    // PV: A = V^T rows (m = d), B = P (n = t, k = s in C-layout regs)
#pragma unroll
    for (int sc = 0; sc < 4; ++sc) {
      int so = ((sc * 2 + (q >> 1)) ^ lx) * 16 + (q & 1) * 8;
#pragma unroll
      for (int dt = 0; dt < 4; ++dt) {
        s4v vv = *(const s4v*)(Vl + (dt * 16 + l) * 128 + so);
        O[dt] = __builtin_amdgcn_mfma_f32_16x16x16bf16_1k(vv, Pf[sc], O[dt], 0, 0, 0);
      }
    }
    __syncthreads();  // staging of j+1 drained; all waves done with buf (j&1)
  }

  // epilogue: lane holds row t = tg, cols d = dt*16 + q*4 + r  -> float4 stores
  float inv = 1.f / lsum;
  int b = bh >> 4, h = bh & 15;
  float* ob = out + ((size_t)b * 2048 + tg) * 1024 + h * 64;
#pragma unroll
  for (int dt = 0; dt < 4; ++dt) {
    f4v val = O[dt] * inv;
    *(f4v*)(ob + dt * 16 + q * 4) = val;
  }
}

extern "C" void kernel_launch(void* const* d_in, const int* in_sizes, int n_in,
                              void* d_out, int out_size, void* d_ws, size_t ws_size,
                              hipStream_t stream) {
  const float* x = (const float*)d_in[0];     // [2,2048,1024]
  const float* W = (const float*)d_in[1];     // [1024,3072]
  const float* bias = (const float*)d_in[2];  // [3072]
  float* out = (float*)d_out;                 // [2,2048,1024]

  char* ws = (char*)d_ws;
  __hip_bfloat16* xb = (__hip_bfloat16*)ws;                    // 8,388,608 B
  __hip_bfloat16* Wt = (__hip_bfloat16*)(ws + 8388608);        // 6,291,456 B
  __hip_bfloat16* Qg = (__hip_bfloat16*)(ws + 14680064);       // 8,388,608 B
  __hip_bfloat16* Kg = (__hip_bfloat16*)(ws + 23068672);       // 8,388,608 B
  __hip_bfloat16* Vt = (__hip_bfloat16*)(ws + 31457280);       // 8,388,608 B

  k_prep<<<7168, 256, 0, stream>>>(x, W, xb, Wt);
  k_gemm<<<dim3(12, 16), 512, 0, stream>>>(xb, Wt, bias, Qg, Kg, Vt);
  k_attn<<<1024, 256, 0, stream>>>(Qg, Kg, Vt, out);
}

// Round 4
// 175.020 us; speedup vs baseline: 1.1093x; 1.1093x over previous
//
#include <hip/hip_runtime.h>
#include <hip/hip_bf16.h>

typedef __attribute__((ext_vector_type(8))) short s8v;    // 8 bf16
typedef __attribute__((ext_vector_type(4))) short s4v;    // 4 bf16
typedef __attribute__((ext_vector_type(4))) float f4v;    // 4 fp32

__device__ __forceinline__ void g2lds16(const void* g, void* l) {
  __builtin_amdgcn_global_load_lds(
      (__attribute__((address_space(1))) void*)(g),
      (__attribute__((address_space(3))) void*)(l), 16, 0, 0);
}

__device__ __forceinline__ short f2bf(float f) {
  __hip_bfloat16 h = __float2bfloat16(f);
  return *reinterpret_cast<short*>(&h);
}

// ---------------- K0: fused x->bf16 cvt  +  W transpose->bf16 ----------------
__global__ void k_prep(const float* __restrict__ x, const float* __restrict__ W,
                       __hip_bfloat16* __restrict__ xb, __hip_bfloat16* __restrict__ Wt) {
  int bx = blockIdx.x;
  if (bx < 4096) {
    int i = (bx * 256 + threadIdx.x) * 4;
    float4 v = *(const float4*)(x + i);
    __hip_bfloat16 o[4] = {__float2bfloat16(v.x), __float2bfloat16(v.y),
                           __float2bfloat16(v.z), __float2bfloat16(v.w)};
    *(uint2*)(xb + i) = *(const uint2*)(o);
  } else {
    __shared__ float tile[32][33];
    int r = bx - 4096;            // 0..3071 = 32 x 96
    int rt = r / 96;              // over 1024/32
    int ct = r - rt * 96;         // over 3072/32
    int c0 = ct * 32, r0 = rt * 32;
    int tr = threadIdx.x >> 5, tc = threadIdx.x & 31;
#pragma unroll
    for (int i = 0; i < 32; i += 8)
      tile[tr + i][tc] = W[(size_t)(r0 + tr + i) * 3072 + c0 + tc];
    __syncthreads();
#pragma unroll
    for (int i = 0; i < 32; i += 8)
      Wt[(size_t)(c0 + tr + i) * 1024 + r0 + tc] = __float2bfloat16(tile[tc][tr + i]);
  }
}

// ---------------- K1: GEMM + fused QKV scatter epilogue ----------------
// (round-0 structure: 128^2 tile, BK=32, 4 waves, 768 blocks, 3 blocks/CU
//  implicit overlap — measured 57.6us / 448 TF. One change vs round 0: the
//  attention softmax scale 0.125*log2e is folded into Q at the epilogue, so
//  k_attn's per-tile S*c1 pass disappears.)
__global__ __launch_bounds__(256) void k_gemm(const __hip_bfloat16* __restrict__ A,
                                              const __hip_bfloat16* __restrict__ Bt,
                                              const float* __restrict__ bias,
                                              __hip_bfloat16* __restrict__ Q,
                                              __hip_bfloat16* __restrict__ K,
                                              __hip_bfloat16* __restrict__ Vt) {
  __shared__ __align__(16) __hip_bfloat16 As[2][128 * 32];
  __shared__ __align__(16) __hip_bfloat16 Bs[2][128 * 32];
  const int tid = threadIdx.x;
  const int lane = tid & 63, wave = tid >> 6;
  const int m0 = blockIdx.y * 128, n0 = blockIdx.x * 128;
  const int wm = (wave & 1) * 64, wn = (wave >> 1) * 64;
  const int lrow = lane & 15;
  const int quad = lane >> 4;

  f4v acc[4][4] = {};

  auto stage = [&](int k0, int kb) {
#pragma unroll
    for (int c = 0; c < 2; ++c) {
      int e = c * 2048 + tid * 8;             // element idx in 128x32 tile
      int row = e >> 5;
      int slot = (e & 31) >> 3;               // 0..3 (8-elem slots)
      int src = k0 + ((slot ^ ((row >> 1) & 3)) << 3);
      g2lds16(A + (size_t)(m0 + row) * 1024 + src, &As[kb][e]);
      g2lds16(Bt + (size_t)(n0 + row) * 1024 + src, &Bs[kb][e]);
    }
  };

  const int swz = (quad ^ ((lrow >> 1) & 3)) * 8;  // swizzled k-slot for frag reads

  stage(0, 0);
  for (int it = 0; it < 32; ++it) {
    __syncthreads();                    // drains stage(it) (issued one iter ago)
    if (it < 31) stage((it + 1) * 32, (it + 1) & 1);
    const __hip_bfloat16* Ab = As[it & 1];
    const __hip_bfloat16* Bb = Bs[it & 1];
    s8v af[4], bfr[4];
#pragma unroll
    for (int mi = 0; mi < 4; ++mi) af[mi] = *(const s8v*)(Ab + (wm + mi * 16 + lrow) * 32 + swz);
#pragma unroll
    for (int ni = 0; ni < 4; ++ni) bfr[ni] = *(const s8v*)(Bb + (wn + ni * 16 + lrow) * 32 + swz);
#pragma unroll
    for (int mi = 0; mi < 4; ++mi)
#pragma unroll
      for (int ni = 0; ni < 4; ++ni)
        acc[mi][ni] = __builtin_amdgcn_mfma_f32_16x16x32_bf16(af[mi], bfr[ni], acc[mi][ni], 0, 0, 0);
  }

  // epilogue: per-row destination decode, d-packed 8B stores for Q/K
  const int cw = n0 + wn;            // multiple of 64 -> c10 wave-uniform
  const int c10 = cw >> 10;          // 0..2
  const int d0 = (cw & 1023) >> 4;   // multiple of 4
  const int h = lrow;
  float bv[4];
#pragma unroll
  for (int ni = 0; ni < 4; ++ni) bv[ni] = bias[cw + ni * 16 + lrow];

#pragma unroll
  for (int mi = 0; mi < 4; ++mi) {
    int rbase = m0 + wm + mi * 16 + quad * 4;
#pragma unroll
    for (int reg = 0; reg < 4; ++reg) {
      int rr = rbase + reg;
      int u = 3 * rr + c10;
      int s = u >> 12;
      int b = (u >> 11) & 1;
      int t = u & 2047;
      if (s < 2) {
        __hip_bfloat16* dst = (s == 0) ? Q : K;
        // Q carries the attention scale: 0.125 * log2(e)
        const float qs = (s == 0) ? 0.18033688011112042f : 1.0f;
        s4v pk;
#pragma unroll
        for (int ni = 0; ni < 4; ++ni) pk[ni] = f2bf((acc[mi][ni][reg] + bv[ni]) * qs);
        *(s4v*)(dst + ((size_t)(b * 16 + h) * 2048 + t) * 64 + d0) = pk;
      } else {
#pragma unroll
        for (int ni = 0; ni < 4; ++ni)
          Vt[((size_t)(b * 16 + h) * 64 + d0 + ni) * 2048 + t] =
              __float2bfloat16(acc[mi][ni][reg] + bv[ni]);
      }
    }
  }
}

// ---------------- K2: causal flash attention ----------------
// 4 waves / block, 64 Q rows (16/wave). K/V tiles staged coalesced via
// global_load_lds into a double-buffered, XOR-swizzled LDS. One barrier per
// KV tile. Q arrives pre-scaled by 0.125*log2e (folded into k_gemm), so S
// is already in the log2 domain. T13 defer-max (THR=8): skip the O/lsum
// rescale when the running max grows by <= 8 — P bounded by 2^8, lsum and O
// scale together and cancel at the final normalization.
__global__ __launch_bounds__(256, 3) void k_attn(const __hip_bfloat16* __restrict__ Q,
                                                 const __hip_bfloat16* __restrict__ K,
                                                 const __hip_bfloat16* __restrict__ Vt,
                                                 float* __restrict__ out) {
  __shared__ __align__(16) char lds[2][16384];  // per buf: K tile 8KB | V tile 8KB

  const int tid = threadIdx.x;
  const int lane = tid & 63, w = tid >> 6;
  const int l = lane & 15, q = lane >> 4, lx = l & 7;

  const int bid = blockIdx.x;           // 1024 blocks
  const int xcd = bid & 7;
  const int idx = bid >> 3;             // 0..127
  const int bh = xcd + 8 * (idx & 3);   // 4 bh per XCD -> 2MB K+V in its L2
  const int qb = 31 - (idx >> 2);       // heavy blocks first; tiles 0..qb

  const char* Kb = (const char*)(K + (size_t)bh * 131072);
  const char* Vb = (const char*)(Vt + (size_t)bh * 131072);
  const __hip_bfloat16* Qp = Q + (size_t)bh * 131072 + (size_t)qb * 4096;

  // Q fragment (load once): B[n=t][k], t = qb*64 + w*16 + l
  s8v Qf[2];
#pragma unroll
  for (int kh = 0; kh < 2; ++kh)
    Qf[kh] = *(const s8v*)(Qp + (size_t)(w * 16 + l) * 64 + kh * 32 + q * 8);

  f4v O[4] = {};
  float m = -INFINITY, lsum = 0.f;
  const int tg = qb * 64 + w * 16 + l;          // this lane's global Q row

  auto stage = [&](int j, char* buf) {
#pragma unroll
    for (int c = 0; c < 4; ++c) {
      int chunk = w * 4 + c;            // 0..15
      int ls = chunk * 64 + lane;       // 16B-slot index
      if (chunk < 8) {                  // K tile: LDS[row][kb] = K[row][kb ^ (row&7)]
        int row = ls >> 3, kb = ls & 7;
        g2lds16(Kb + (size_t)j * 8192 + row * 128 + ((kb ^ (row & 7)) << 4),
                buf + ls * 16);
      } else {                          // V tile: LDS[d][kb] = V^T[d][kb ^ (d&7)]
        int ls2 = ls - 512;
        int d = ls2 >> 3, kb = ls2 & 7;
        g2lds16(Vb + (size_t)d * 4096 + (size_t)j * 128 + ((kb ^ (d & 7)) << 4),
                buf + 8192 + ls2 * 16);
      }
    }
  };

  stage(0, lds[0]);
  __syncthreads();

  for (int j = 0; j <= qb; ++j) {
    const char* Kl = lds[j & 1];
    const char* Vl = Kl + 8192;
    if (j < qb) stage(j + 1, lds[(j + 1) & 1]);

    // S^T: A = K rows (m = s_local), B = Q (n = t); S already log2-scaled
    f4v S[4];
#pragma unroll
    for (int nt = 0; nt < 4; ++nt) {
      const char* rowp = Kl + (nt * 16 + l) * 128;
      s8v k0 = *(const s8v*)(rowp + ((q ^ lx) << 4));
      s8v k1 = *(const s8v*)(rowp + (((4 + q) ^ lx) << 4));
      f4v z = {0.f, 0.f, 0.f, 0.f};
      z = __builtin_amdgcn_mfma_f32_16x16x32_bf16(k0, Qf[0], z, 0, 0, 0);
      z = __builtin_amdgcn_mfma_f32_16x16x32_bf16(k1, Qf[1], z, 0, 0, 0);
      S[nt] = z;
    }

    if (j == qb) {
#pragma unroll
      for (int nt = 0; nt < 4; ++nt)
#pragma unroll
        for (int r = 0; r < 4; ++r)
          if (j * 64 + nt * 16 + q * 4 + r > tg) S[nt][r] = -1e30f;
    }

    float mx = S[0][0];
#pragma unroll
    for (int nt = 0; nt < 4; ++nt)
#pragma unroll
      for (int r = 0; r < 4; ++r) mx = fmaxf(mx, S[nt][r]);
    mx = fmaxf(mx, __shfl_xor(mx, 16));
    mx = fmaxf(mx, __shfl_xor(mx, 32));

    // T13 defer-max: rescale only when the max grew by > 8 (wave-uniform)
    if (!__all(mx - m <= 8.f)) {
      float mn = fmaxf(m, mx);
      float alpha = exp2f(m - mn);
      m = mn;
      lsum *= alpha;
#pragma unroll
      for (int dt = 0; dt < 4; ++dt) O[dt] *= alpha;
    }

    float rs = 0.f;
    s4v Pf[4];
#pragma unroll
    for (int nt = 0; nt < 4; ++nt)
#pragma unroll
      for (int r = 0; r < 4; ++r) {
        float e = exp2f(S[nt][r] - m);
        rs += e;
        Pf[nt][r] = f2bf(e);
      }
    rs += __shfl_xor(rs, 16);
    rs += __shfl_xor(rs, 32);
    lsum += rs;

    // PV: A = V^T rows (m = d), B = P (n = t, k = s in C-layout regs)
#pragma unroll
    for (int sc = 0; sc < 4; ++sc) {
      int so = ((sc * 2 + (q >> 1)) ^ lx) * 16 + (q & 1) * 8;
#pragma unroll
      for (int dt = 0; dt < 4; ++dt) {
        s4v vv = *(const s4v*)(Vl + (dt * 16 + l) * 128 + so);
        O[dt] = __builtin_amdgcn_mfma_f32_16x16x16bf16_1k(vv, Pf[sc], O[dt], 0, 0, 0);
      }
    }
    __syncthreads();  // staging of j+1 drained; all waves done with buf (j&1)
  }

  // epilogue: lane holds row t = tg, cols d = dt*16 + q*4 + r  -> float4 stores
  float inv = 1.f / lsum;
  int b = bh >> 4, h = bh & 15;
  float* ob = out + ((size_t)b * 2048 + tg) * 1024 + h * 64;
#pragma unroll
  for (int dt = 0; dt < 4; ++dt) {
    f4v val = O[dt] * inv;
    *(f4v*)(ob + dt * 16 + q * 4) = val;
  }
}

extern "C" void kernel_launch(void* const* d_in, const int* in_sizes, int n_in,
                              void* d_out, int out_size, void* d_ws, size_t ws_size,
                              hipStream_t stream) {
  const float* x = (const float*)d_in[0];     // [2,2048,1024]
  const float* W = (const float*)d_in[1];     // [1024,3072]
  const float* bias = (const float*)d_in[2];  // [3072]
  float* out = (float*)d_out;                 // [2,2048,1024]

  char* ws = (char*)d_ws;
  __hip_bfloat16* xb = (__hip_bfloat16*)ws;                    // 8,388,608 B
  __hip_bfloat16* Wt = (__hip_bfloat16*)(ws + 8388608);        // 6,291,456 B
  __hip_bfloat16* Qg = (__hip_bfloat16*)(ws + 14680064);       // 8,388,608 B
  __hip_bfloat16* Kg = (__hip_bfloat16*)(ws + 23068672);       // 8,388,608 B
  __hip_bfloat16* Vt = (__hip_bfloat16*)(ws + 31457280);       // 8,388,608 B

  k_prep<<<7168, 256, 0, stream>>>(x, W, xb, Wt);
  k_gemm<<<dim3(24, 32), 256, 0, stream>>>(xb, Wt, bias, Qg, Kg, Vt);
  k_attn<<<1024, 256, 0, stream>>>(Qg, Kg, Vt, out);
}